// Round 1
// baseline (13219.498 us; speedup 1.0000x reference)
//
#include <hip/hip_runtime.h>
#include <hip/hip_bf16.h>
#include <stdint.h>

// Problem dims (fixed)
#define Bn   2
#define Tn   1024
#define NTOK 2048      // B*T
#define Vn   32000
#define En   512
#define Hn   768
#define H3   2304      // 3*H
#define Mn   256
#define Rn   64
#define Gn   16

typedef __attribute__((ext_vector_type(8))) short short8;
typedef __attribute__((ext_vector_type(4))) float f32x4;

__device__ __forceinline__ float sigmoidf_(float x) { return 1.f / (1.f + __expf(-x)); }

__device__ __forceinline__ unsigned short f2bf(float x) {
    union { float f; unsigned u; } v; v.f = x;
    unsigned r = v.u + 0x7fffu + ((v.u >> 16) & 1u);   // RNE
    return (unsigned short)(r >> 16);
}

// ---------------------------------------------------------------------------
// Generic fp32 GEMM: C = act(A @ B^T + bias). Optional A row-gather (embedding).
// Tiles 64x64, BK=16, 256 threads, 4x4 per thread. Batched via blockIdx.z.
// ACT: 0=none, 1=sigmoid, 2=relu^2
// ---------------------------------------------------------------------------
template<int ACT>
__global__ __launch_bounds__(256) void gemm_nt_f32(
    const float* __restrict__ A, const float* __restrict__ B,
    float* __restrict__ C, const float* __restrict__ bias,
    int M, int N, int K, long sA, long sB, long sC,
    const int* __restrict__ gatherA)
{
    A += blockIdx.z * sA; B += blockIdx.z * sB; C += blockIdx.z * sC;
    __shared__ float As[16][68];
    __shared__ float Bs[16][68];
    const int m0 = blockIdx.y * 64, n0 = blockIdx.x * 64;
    const int tid = threadIdx.x;
    const int tx = tid & 15, ty = tid >> 4;
    float acc[4][4] = {};
    for (int k0 = 0; k0 < K; k0 += 16) {
        #pragma unroll
        for (int i = 0; i < 4; i++) {
            int idx = tid + i * 256;
            int r = idx >> 4, c = idx & 15;
            int gm = m0 + r;
            float va = 0.f;
            if (gm < M) { int ar = gatherA ? gatherA[gm] : gm; va = A[(long)ar * K + k0 + c]; }
            As[c][r] = va;
            int gn = n0 + r;
            float vb = 0.f;
            if (gn < N) vb = B[(long)gn * K + k0 + c];
            Bs[c][r] = vb;
        }
        __syncthreads();
        #pragma unroll
        for (int kk = 0; kk < 16; kk++) {
            float4 a4 = *(const float4*)&As[kk][ty * 4];
            float4 b4 = *(const float4*)&Bs[kk][tx * 4];
            float a[4] = {a4.x, a4.y, a4.z, a4.w};
            float b[4] = {b4.x, b4.y, b4.z, b4.w};
            #pragma unroll
            for (int i = 0; i < 4; i++)
                #pragma unroll
                for (int j = 0; j < 4; j++) acc[i][j] += a[i] * b[j];
        }
        __syncthreads();
    }
    #pragma unroll
    for (int i = 0; i < 4; i++) {
        int gm = m0 + ty * 4 + i; if (gm >= M) continue;
        #pragma unroll
        for (int j = 0; j < 4; j++) {
            int gn = n0 + tx * 4 + j; if (gn >= N) continue;
            float v = acc[i][j] + (bias ? bias[gn] : 0.f);
            if (ACT == 1) v = sigmoidf_(v);
            if (ACT == 2) { v = fmaxf(v, 0.f); v = v * v; }
            C[(long)gm * N + gn] = v;
        }
    }
}

// C = A @ B (B row-major K x N). Batched. No bias/act.
__global__ __launch_bounds__(256) void gemm_nn_f32(
    const float* __restrict__ A, const float* __restrict__ B,
    float* __restrict__ C, int M, int N, int K, long sA, long sB, long sC)
{
    A += blockIdx.z * sA; B += blockIdx.z * sB; C += blockIdx.z * sC;
    __shared__ float As[16][68];
    __shared__ float Bs[16][68];
    const int m0 = blockIdx.y * 64, n0 = blockIdx.x * 64;
    const int tid = threadIdx.x;
    const int tx = tid & 15, ty = tid >> 4;
    float acc[4][4] = {};
    for (int k0 = 0; k0 < K; k0 += 16) {
        #pragma unroll
        for (int i = 0; i < 4; i++) {
            int idx = tid + i * 256;
            int r = idx >> 4, c = idx & 15;
            int gm = m0 + r;
            As[c][r] = (gm < M) ? A[(long)gm * K + k0 + c] : 0.f;
            int kk2 = idx >> 6, n = idx & 63;
            int gn = n0 + n;
            Bs[kk2][n] = (gn < N) ? B[(long)(k0 + kk2) * N + gn] : 0.f;
        }
        __syncthreads();
        #pragma unroll
        for (int kk = 0; kk < 16; kk++) {
            float4 a4 = *(const float4*)&As[kk][ty * 4];
            float4 b4 = *(const float4*)&Bs[kk][tx * 4];
            float a[4] = {a4.x, a4.y, a4.z, a4.w};
            float b[4] = {b4.x, b4.y, b4.z, b4.w};
            #pragma unroll
            for (int i = 0; i < 4; i++)
                #pragma unroll
                for (int j = 0; j < 4; j++) acc[i][j] += a[i] * b[j];
        }
        __syncthreads();
    }
    #pragma unroll
    for (int i = 0; i < 4; i++) {
        int gm = m0 + ty * 4 + i; if (gm >= M) continue;
        #pragma unroll
        for (int j = 0; j < 4; j++) {
            int gn = n0 + tx * 4 + j; if (gn >= N) continue;
            C[(long)gm * N + gn] = acc[i][j];
        }
    }
}

// ---------------------------------------------------------------------------
// GRU scan: persistent kernel, 64 workgroups x 256. wg owns 12 h-elems;
// W_hh rows live in VGPRs; h exchanged via ping-pong global buffer + counter
// barrier (agent-scope atomics for cross-XCD visibility).
// ---------------------------------------------------------------------------
#define GRU_NWG 64
__global__ __launch_bounds__(256) void gru_scan_k(
    const float* __restrict__ xi, const float* __restrict__ Whh,
    const float* __restrict__ bhh, float* __restrict__ states,
    float* __restrict__ hbuf, unsigned* __restrict__ cnt)
{
    const int wg = blockIdx.x;
    const int tid = threadIdx.x;
    const int wv = tid >> 6, lane = tid & 63;
    const int jbase = wg * 12 + wv * 3;          // wave handles j in [jbase, jbase+3)
    __shared__ float h_lds[2 * Hn];

    // weights: ri = gate*3+q -> row = gate*Hn + jbase + q ; lane covers cols [lane*12, lane*12+12)
    float wreg[9][12];
    #pragma unroll
    for (int ri = 0; ri < 9; ri++) {
        int gate = ri / 3, q = ri % 3;
        const float* wp = Whh + (long)(gate * Hn + jbase + q) * Hn + lane * 12;
        float4 w0 = *(const float4*)(wp);
        float4 w1 = *(const float4*)(wp + 4);
        float4 w2 = *(const float4*)(wp + 8);
        wreg[ri][0] = w0.x; wreg[ri][1] = w0.y; wreg[ri][2]  = w0.z; wreg[ri][3]  = w0.w;
        wreg[ri][4] = w1.x; wreg[ri][5] = w1.y; wreg[ri][6]  = w1.z; wreg[ri][7]  = w1.w;
        wreg[ri][8] = w2.x; wreg[ri][9] = w2.y; wreg[ri][10] = w2.z; wreg[ri][11] = w2.w;
    }
    const bool fin = (lane < 6);
    const int fq = lane >> 1, fb = lane & 1;     // finalize lanes: (q, batch)
    const int fj = jbase + fq;
    float bh0 = 0.f, bh1 = 0.f, bh2 = 0.f;
    if (fin) { bh0 = bhh[fj]; bh1 = bhh[Hn + fj]; bh2 = bhh[2 * Hn + fj]; }

    for (int t = 0; t < Tn; t++) {
        for (int i = tid; i < 2 * Hn; i += 256)
            h_lds[i] = __hip_atomic_load(hbuf + (t & 1) * 2 * Hn + i,
                                         __ATOMIC_RELAXED, __HIP_MEMORY_SCOPE_AGENT);
        __syncthreads();
        float xr = 0.f, xz = 0.f, xn = 0.f;
        if (fin) {
            const float* xp = xi + ((long)fb * Tn + t) * H3 + fj;
            xr = xp[0]; xz = xp[Hn]; xn = xp[2 * Hn];
        }
        float hv0[12], hv1[12];
        {
            const float* hp0 = h_lds + lane * 12;
            const float* hp1 = h_lds + Hn + lane * 12;
            #pragma unroll
            for (int c = 0; c < 12; c++) { hv0[c] = hp0[c]; hv1[c] = hp1[c]; }
        }
        float acc[9][2];
        #pragma unroll
        for (int ri = 0; ri < 9; ri++) {
            float s0 = 0.f, s1 = 0.f;
            #pragma unroll
            for (int c = 0; c < 12; c++) { s0 += wreg[ri][c] * hv0[c]; s1 += wreg[ri][c] * hv1[c]; }
            acc[ri][0] = s0; acc[ri][1] = s1;
        }
        #pragma unroll
        for (int m = 1; m < 64; m <<= 1) {
            #pragma unroll
            for (int ri = 0; ri < 9; ri++) {
                acc[ri][0] += __shfl_xor(acc[ri][0], m, 64);
                acc[ri][1] += __shfl_xor(acc[ri][1], m, 64);
            }
        }
        if (fin) {
            float rsel[3], zsel[3], nsel[3];
            #pragma unroll
            for (int q2 = 0; q2 < 3; q2++) {
                rsel[q2] = fb ? acc[q2][1]     : acc[q2][0];
                zsel[q2] = fb ? acc[3 + q2][1] : acc[3 + q2][0];
                nsel[q2] = fb ? acc[6 + q2][1] : acc[6 + q2][0];
            }
            float hr = (fq == 0) ? rsel[0] : ((fq == 1) ? rsel[1] : rsel[2]);
            float hz = (fq == 0) ? zsel[0] : ((fq == 1) ? zsel[1] : zsel[2]);
            float hnv = (fq == 0) ? nsel[0] : ((fq == 1) ? nsel[1] : nsel[2]);
            hr += bh0; hz += bh1; hnv += bh2;
            float rr = sigmoidf_(xr + hr);
            float zz = sigmoidf_(xz + hz);
            float nn = tanhf(xn + rr * hnv);
            float hp = h_lds[fb * Hn + fj];
            float hnew = (1.f - zz) * nn + zz * hp;
            __hip_atomic_store(hbuf + ((t + 1) & 1) * 2 * Hn + fb * Hn + fj, hnew,
                               __ATOMIC_RELAXED, __HIP_MEMORY_SCOPE_AGENT);
            states[((long)fb * Tn + t) * Hn + fj] = hnew;
        }
        // grid barrier (counter, monotone target)
        __syncthreads();
        if (tid == 0) {
            __threadfence();
            __hip_atomic_fetch_add(cnt, 1u, __ATOMIC_ACQ_REL, __HIP_MEMORY_SCOPE_AGENT);
            unsigned target = (unsigned)(t + 1) * GRU_NWG;
            while (__hip_atomic_load(cnt, __ATOMIC_ACQUIRE, __HIP_MEMORY_SCOPE_AGENT) < target)
                __builtin_amdgcn_s_sleep(2);
            __threadfence();
        }
        __syncthreads();
    }
}

// ---------------------------------------------------------------------------
// Attention softmax (strictly causal, in-place over scores buffer).
// ---------------------------------------------------------------------------
__global__ __launch_bounds__(256) void attn_softmax_k(float* __restrict__ attn)
{
    const int t = blockIdx.x, b = blockIdx.y;
    float* row = attn + ((long)b * Tn + t) * Tn;
    const int tid = threadIdx.x;
    __shared__ float red[256];
    const float scale = 0.0625f;  // 1/sqrt(256)
    float mx = -3.4e38f;
    for (int s = tid; s < t; s += 256) mx = fmaxf(mx, row[s] * scale);
    red[tid] = mx; __syncthreads();
    for (int st = 128; st > 0; st >>= 1) { if (tid < st) red[tid] = fmaxf(red[tid], red[tid + st]); __syncthreads(); }
    mx = red[0]; __syncthreads();
    float sum = 0.f;
    for (int s = tid; s < t; s += 256) { float e = __expf(row[s] * scale - mx); row[s] = e; sum += e; }
    red[tid] = sum; __syncthreads();
    for (int st = 128; st > 0; st >>= 1) { if (tid < st) red[tid] += red[tid + st]; __syncthreads(); }
    sum = red[0];
    float inv = 1.f / fmaxf(sum, 1e-6f);
    for (int s = tid; s < t; s += 256) row[s] *= inv;
    for (int s = t + tid; s < Tn; s += 256) row[s] = 0.f;
}

// top-2 of 16 router logits + 2-way softmax (tie -> lowest index, matches top_k)
__global__ void route_topk_k(const float* __restrict__ rl, float* __restrict__ rw, int* __restrict__ ridx)
{
    int n = blockIdx.x * blockDim.x + threadIdx.x;
    if (n >= NTOK) return;
    const float* r = rl + (long)n * Gn;
    float v1 = -3.4e38f; int i1 = 0;
    #pragma unroll
    for (int g = 0; g < Gn; g++) { float v = r[g]; if (v > v1) { v1 = v; i1 = g; } }
    float v2 = -3.4e38f; int i2 = 0;
    #pragma unroll
    for (int g = 0; g < Gn; g++) { if (g == i1) continue; float v = r[g]; if (v > v2) { v2 = v; i2 = g; } }
    float e2 = __expf(v2 - v1);
    float s = 1.f + e2;
    rw[n * 2] = 1.f / s; rw[n * 2 + 1] = e2 / s;
    ridx[n * 2] = i1; ridx[n * 2 + 1] = i2;
}

// routed basis: out[n][r] += w_g * (inp[n,:] @ cw[g,:,r] + cb[g,r]) for g in top2(n)
// grid: (G, NTOK/256). Accumulate via atomicAdd (out pre-zeroed).
__global__ __launch_bounds__(256) void routed_basis_k(
    const float* __restrict__ inp, const float* __restrict__ cw, const float* __restrict__ cb,
    const float* __restrict__ rw, const int* __restrict__ ridx,
    float* __restrict__ out, int D)
{
    const int g = blockIdx.x;
    const int t0 = blockIdx.y * 256;
    __shared__ float srow[Hn];
    __shared__ float part[4][64];
    const int r = threadIdx.x & 63, dq = threadIdx.x >> 6;
    const float* cwg = cw + (long)g * D * Rn;
    const int dlen = D >> 2;
    for (int ti = 0; ti < 256; ti++) {
        const int n = t0 + ti;
        float wt = 0.f;
        if (ridx[n * 2] == g) wt = rw[n * 2];
        else if (ridx[n * 2 + 1] == g) wt = rw[n * 2 + 1];
        if (wt == 0.f) continue;            // block-uniform
        __syncthreads();
        for (int d = threadIdx.x; d < D; d += 256) srow[d] = inp[(long)n * D + d];
        __syncthreads();
        float p = 0.f;
        const int dbeg = dq * dlen;
        for (int d = dbeg; d < dbeg + dlen; d++) p += srow[d] * cwg[(long)d * Rn + r];
        part[dq][r] = p;
        __syncthreads();
        if (dq == 0) {
            float sv = part[0][r] + part[1][r] + part[2][r] + part[3][r] + cb[g * Rn + r];
            atomicAdd(&out[(long)n * Rn + r], wt * sv);
        }
    }
}

__global__ void comb_k(const float* __restrict__ bb, const float* __restrict__ mb,
                       const float* __restrict__ bg, const float* __restrict__ bs_ptr,
                       float* __restrict__ comb)
{
    int i = blockIdx.x * 256 + threadIdx.x;
    if (i < NTOK * Rn) comb[i] = bb[i] + bs_ptr[0] * (bg[i] * mb[i]);
}

__global__ void ftotal_k(const float* __restrict__ bf, const float* __restrict__ dl,
                         unsigned short* __restrict__ outb)
{
    int i = blockIdx.x * 256 + threadIdx.x;
    if (i < NTOK * En) outb[i] = f2bf(bf[i] + dl[i]);
}

__global__ void embconv_k(const float* __restrict__ emb, unsigned short* __restrict__ outb)
{
    long i = (long)(blockIdx.x * 256 + threadIdx.x) * 4;
    const long nTot = (long)Vn * En;
    for (; i < nTot; i += (long)gridDim.x * 256 * 4) {
        float4 v = *(const float4*)(emb + i);
        ushort4 u;
        u.x = f2bf(v.x); u.y = f2bf(v.y); u.z = f2bf(v.z); u.w = f2bf(v.w);
        *(ushort4*)(outb + i) = u;
    }
}

// ---------------------------------------------------------------------------
// Logits GEMM: C(2048,32000) = A(2048,512)bf16 @ B(32000,512)bf16^T + bias.
// m97-style: 128x128 tile, BK=32, 4 waves (2x2), 16x16x32 bf16 MFMA,
// global_load_lds width-16 staging.
// ---------------------------------------------------------------------------
typedef const __attribute__((address_space(1))) void* as1cv_t;
typedef __attribute__((address_space(3))) void* as3v_t;
__device__ __forceinline__ void gload_lds16(const void* g, void* l) {
    __builtin_amdgcn_global_load_lds((as1cv_t)g, (as3v_t)l, 16, 0, 0);
}

__global__ __launch_bounds__(256) void logits_mfma_k(
    const unsigned short* __restrict__ Abf, const unsigned short* __restrict__ Bbf,
    const float* __restrict__ bias, float* __restrict__ C)
{
    __shared__ __align__(16) unsigned short As[128 * 32];
    __shared__ __align__(16) unsigned short Bs[128 * 32];
    const int n0 = blockIdx.x * 128;
    const int m0 = blockIdx.y * 128;
    const int tid = threadIdx.x;
    const int lane = tid & 63, wv = tid >> 6;
    const int wr = wv >> 1, wc = wv & 1;
    f32x4 zero4 = {0.f, 0.f, 0.f, 0.f};
    f32x4 acc[4][4];
    #pragma unroll
    for (int i = 0; i < 4; i++)
        #pragma unroll
        for (int j = 0; j < 4; j++) acc[i][j] = zero4;

    const int lrow = lane & 15, lko = (lane >> 4) * 8;

    for (int k0 = 0; k0 < En; k0 += 32) {
        __syncthreads();
        #pragma unroll
        for (int i = 0; i < 2; i++) {
            int base = i * 4096 + wv * 1024;     // wave-uniform LDS byte offset
            int p = base + lane * 16;            // this lane's element position
            int row = p >> 6, cb = p & 63;       // 64 B per tile row (32 bf16)
            gload_lds16((const char*)Abf + ((long)(m0 + row) * En + k0) * 2 + cb, (char*)As + base);
            gload_lds16((const char*)Bbf + ((long)(n0 + row) * En + k0) * 2 + cb, (char*)Bs + base);
        }
        __syncthreads();
        short8 af[4], bfr[4];
        #pragma unroll
        for (int m = 0; m < 4; m++)
            af[m] = *(const short8*)((const char*)As + (wr * 64 + m * 16 + lrow) * 64 + lko * 2);
        #pragma unroll
        for (int n = 0; n < 4; n++)
            bfr[n] = *(const short8*)((const char*)Bs + (wc * 64 + n * 16 + lrow) * 64 + lko * 2);
        #pragma unroll
        for (int m = 0; m < 4; m++)
            #pragma unroll
            for (int n = 0; n < 4; n++)
                acc[m][n] = __builtin_amdgcn_mfma_f32_16x16x32_bf16(af[m], bfr[n], acc[m][n], 0, 0, 0);
    }
    const int orow = (lane >> 4) * 4, ocol = lane & 15;
    #pragma unroll
    for (int m = 0; m < 4; m++) {
        #pragma unroll
        for (int n = 0; n < 4; n++) {
            int col = n0 + wc * 64 + n * 16 + ocol;
            float bv = bias[col];
            int rbase = m0 + wr * 64 + m * 16 + orow;
            #pragma unroll
            for (int r2 = 0; r2 < 4; r2++)
                C[(long)(rbase + r2) * Vn + col] = acc[m][n][r2] + bv;
        }
    }
}

// copy mechanism: logits[b,t, ids[b,s]] += attn[b,t,s] * eg[b,t] * exact_scale
__global__ __launch_bounds__(256) void copy_scatter_k(
    float* __restrict__ logits, const float* __restrict__ attn,
    const float* __restrict__ eg, const int* __restrict__ ids,
    const float* __restrict__ esc)
{
    const int n = blockIdx.x;
    const int b = n >> 10, t = n & 1023;
    const float g = eg[n] * esc[0];
    const float* arow = attn + ((long)b * Tn + t) * Tn;
    float* lrow = logits + (long)n * Vn;
    const int* idrow = ids + b * Tn;
    for (int s = threadIdx.x; s < t; s += 256) {
        float a = arow[s];
        atomicAdd(lrow + idrow[s], a * g);
    }
}

// ---------------------------------------------------------------------------
extern "C" void kernel_launch(void* const* d_in, const int* in_sizes, int n_in,
                              void* d_out, int out_size, void* d_ws, size_t ws_size,
                              hipStream_t stream)
{
    const int*   ids      = (const int*)  d_in[0];
    const float* emb      = (const float*)d_in[1];
    const float* W_ih     = (const float*)d_in[2];
    const float* W_hh     = (const float*)d_in[3];
    const float* b_ih     = (const float*)d_in[4];
    const float* b_hh     = (const float*)d_in[5];
    const float* Wq       = (const float*)d_in[6];
    const float* bq       = (const float*)d_in[7];
    const float* Wk       = (const float*)d_in[8];
    const float* bk       = (const float*)d_in[9];
    const float* Wg       = (const float*)d_in[10];
    const float* bg       = (const float*)d_in[11];
    const float* Whf      = (const float*)d_in[12];
    const float* bhf      = (const float*)d_in[13];
    const float* Whp      = (const float*)d_in[14];
    const float* bhp      = (const float*)d_in[15];
    const float* Wr       = (const float*)d_in[16];
    const float* br       = (const float*)d_in[17];
    const float* base_cw  = (const float*)d_in[18];
    const float* base_cb  = (const float*)d_in[19];
    const float* mem_cw   = (const float*)d_in[20];
    const float* mem_cb   = (const float*)d_in[21];
    const float* Wbg      = (const float*)d_in[22];
    const float* bbg      = (const float*)d_in[23];
    const float* Wbu      = (const float*)d_in[24];
    const float* out_bias = (const float*)d_in[25];
    const float* esc      = (const float*)d_in[26];
    const float* bsc      = (const float*)d_in[27];
    float* logits = (float*)d_out;

    char* ws = (char*)d_ws;
    size_t off = 0;
    auto alloc = [&](size_t bytes) -> void* {
        void* p = ws + off; off = (off + bytes + 255) & ~(size_t)255; return p;
    };
    float* xi     = (float*)alloc((size_t)NTOK * H3 * 4);   // reused as 'head' after GRU
    float* head   = xi;                                     // 2048*2048 <= 2048*2304
    float* states = (float*)alloc((size_t)NTOK * Hn * 4);
    float* hbuf   = (float*)alloc((size_t)2 * 2 * Hn * 4);  // ping-pong h, 12288 B (256-mult)
    unsigned* cnt = (unsigned*)alloc(256);                  // barrier counter (adjacent to hbuf)
    float* bfeat  = (float*)alloc((size_t)NTOK * En * 4);
    float* qb     = (float*)alloc((size_t)NTOK * Mn * 4);
    float* kb     = (float*)alloc((size_t)NTOK * Mn * 4);
    float* attn   = (float*)alloc((size_t)Bn * Tn * Tn * 4);
    float* mem    = (float*)alloc((size_t)NTOK * Hn * 4);
    float* rl     = (float*)alloc((size_t)NTOK * Gn * 4);
    float* rw     = (float*)alloc((size_t)NTOK * 2 * 4);
    int*   ridx   = (int*)  alloc((size_t)NTOK * 2 * 4);
    float* bgate  = (float*)alloc((size_t)NTOK * Rn * 4);
    float* egb    = (float*)alloc((size_t)NTOK * 4);
    float* bb     = (float*)alloc((size_t)NTOK * Rn * 4);   // 524288 B (256-mult, mb adjacent)
    float* mb     = (float*)alloc((size_t)NTOK * Rn * 4);
    float* comb   = (float*)alloc((size_t)NTOK * Rn * 4);
    float* delta  = (float*)alloc((size_t)NTOK * En * 4);
    unsigned short* fbf   = (unsigned short*)alloc((size_t)NTOK * En * 2);
    unsigned short* embbf = (unsigned short*)alloc((size_t)Vn * En * 2);
    (void)in_sizes; (void)n_in; (void)out_size; (void)ws_size;

    // zero: h ping-pong + barrier counter ; basis accumulators
    hipMemsetAsync(hbuf, 0, (size_t)2 * 2 * Hn * 4 + 256, stream);
    hipMemsetAsync(bb, 0, (size_t)NTOK * Rn * 4 * 2, stream);

    // emb -> bf16 (for tied-embedding MFMA GEMM)
    embconv_k<<<2048, 256, 0, stream>>>(emb, embbf);
    // xi = emb[ids] @ W_ih^T + b_ih   (gathered A)
    gemm_nt_f32<0><<<dim3(H3 / 64, NTOK / 64, 1), 256, 0, stream>>>(
        emb, W_ih, xi, b_ih, NTOK, H3, En, 0, 0, 0, ids);
    // GRU scan (persistent, grid barrier)
    gru_scan_k<<<GRU_NWG, 256, 0, stream>>>(xi, W_hh, b_hh, states, hbuf, cnt);
    // head = relu(states @ Whf^T + bhf)^2   (overwrites xi buffer)
    gemm_nt_f32<2><<<dim3(2048 / 64, NTOK / 64), 256, 0, stream>>>(
        states, Whf, head, bhf, NTOK, 4 * En, Hn, 0, 0, 0, nullptr);
    // base_feat = head @ Whp^T + bhp
    gemm_nt_f32<0><<<dim3(En / 64, NTOK / 64), 256, 0, stream>>>(
        head, Whp, bfeat, bhp, NTOK, En, 4 * En, 0, 0, 0, nullptr);
    // router
    gemm_nt_f32<0><<<dim3(1, NTOK / 64), 256, 0, stream>>>(
        states, Wr, rl, br, NTOK, Gn, Hn, 0, 0, 0, nullptr);
    route_topk_k<<<NTOK / 256, 256, 0, stream>>>(rl, rw, ridx);
    // q, k
    gemm_nt_f32<0><<<dim3(Mn / 64, NTOK / 64), 256, 0, stream>>>(
        states, Wq, qb, bq, NTOK, Mn, Hn, 0, 0, 0, nullptr);
    gemm_nt_f32<0><<<dim3(Mn / 64, NTOK / 64), 256, 0, stream>>>(
        states, Wk, kb, bk, NTOK, Mn, Hn, 0, 0, 0, nullptr);
    // scores (scale folded into softmax), then causal softmax in-place
    gemm_nt_f32<0><<<dim3(Tn / 64, Tn / 64, Bn), 256, 0, stream>>>(
        qb, kb, attn, nullptr, Tn, Tn, Mn, (long)Tn * Mn, (long)Tn * Mn, (long)Tn * Tn, nullptr);
    attn_softmax_k<<<dim3(Tn, Bn), 256, 0, stream>>>(attn);
    // mem_states = attn @ states
    gemm_nn_f32<<<dim3(Hn / 64, Tn / 64, Bn), 256, 0, stream>>>(
        attn, states, mem, Tn, Hn, Tn, (long)Tn * Tn, (long)Tn * Hn, (long)Tn * Hn);
    // gates
    gemm_nt_f32<1><<<dim3(1, NTOK / 64), 256, 0, stream>>>(
        states, Wbg, bgate, bbg, NTOK, Rn, Hn, 0, 0, 0, nullptr);
    gemm_nt_f32<1><<<dim3(1, NTOK / 64), 256, 0, stream>>>(
        states, Wg, egb, bg, NTOK, 1, Hn, 0, 0, 0, nullptr);
    // routed bases (top-2 sparse)
    routed_basis_k<<<dim3(Gn, NTOK / 256), 256, 0, stream>>>(bfeat, base_cw, base_cb, rw, ridx, bb, En);
    routed_basis_k<<<dim3(Gn, NTOK / 256), 256, 0, stream>>>(mem, mem_cw, mem_cb, rw, ridx, mb, Hn);
    // delta = (bb + bs*bgate*mb) @ Wbu^T ; f_total = bf16(base_feat + delta)
    comb_k<<<(NTOK * Rn + 255) / 256, 256, 0, stream>>>(bb, mb, bgate, bsc, comb);
    gemm_nt_f32<0><<<dim3(En / 64, NTOK / 64), 256, 0, stream>>>(
        comb, Wbu, delta, nullptr, NTOK, En, Rn, 0, 0, 0, nullptr);
    ftotal_k<<<(NTOK * En + 255) / 256, 256, 0, stream>>>(bfeat, delta, fbf);
    // logits = f_total @ emb^T + out_bias  (both emb matmuls folded into one)
    logits_mfma_k<<<dim3(Vn / 128, NTOK / 128), 256, 0, stream>>>(fbf, embbf, out_bias, logits);
    // copy mechanism scatter
    copy_scatter_k<<<NTOK, 256, 0, stream>>>(logits, attn, egb, ids, esc);
}

// Round 2
// 7602.899 us; speedup vs baseline: 1.7387x; 1.7387x over previous
//
#include <hip/hip_runtime.h>
#include <hip/hip_bf16.h>
#include <stdint.h>

// Problem dims (fixed)
#define Bn   2
#define Tn   1024
#define NTOK 2048      // B*T
#define Vn   32000
#define En   512
#define Hn   768
#define H3   2304      // 3*H
#define Mn   256
#define Rn   64
#define Gn   16

typedef __attribute__((ext_vector_type(8))) short short8;
typedef __attribute__((ext_vector_type(4))) float f32x4;

__device__ __forceinline__ float sigmoidf_(float x) { return 1.f / (1.f + __expf(-x)); }

__device__ __forceinline__ unsigned short f2bf(float x) {
    union { float f; unsigned u; } v; v.f = x;
    unsigned r = v.u + 0x7fffu + ((v.u >> 16) & 1u);   // RNE
    return (unsigned short)(r >> 16);
}

// ---------------------------------------------------------------------------
// Generic fp32 GEMM: C = act(A @ B^T + bias). Optional A row-gather (embedding).
// Tiles 64x64, BK=16, 256 threads, 4x4 per thread. Batched via blockIdx.z.
// ACT: 0=none, 1=sigmoid, 2=relu^2
// ---------------------------------------------------------------------------
template<int ACT>
__global__ __launch_bounds__(256) void gemm_nt_f32(
    const float* __restrict__ A, const float* __restrict__ B,
    float* __restrict__ C, const float* __restrict__ bias,
    int M, int N, int K, long sA, long sB, long sC,
    const int* __restrict__ gatherA)
{
    A += blockIdx.z * sA; B += blockIdx.z * sB; C += blockIdx.z * sC;
    __shared__ float As[16][68];
    __shared__ float Bs[16][68];
    const int m0 = blockIdx.y * 64, n0 = blockIdx.x * 64;
    const int tid = threadIdx.x;
    const int tx = tid & 15, ty = tid >> 4;
    float acc[4][4] = {};
    for (int k0 = 0; k0 < K; k0 += 16) {
        #pragma unroll
        for (int i = 0; i < 4; i++) {
            int idx = tid + i * 256;
            int r = idx >> 4, c = idx & 15;
            int gm = m0 + r;
            float va = 0.f;
            if (gm < M) { int ar = gatherA ? gatherA[gm] : gm; va = A[(long)ar * K + k0 + c]; }
            As[c][r] = va;
            int gn = n0 + r;
            float vb = 0.f;
            if (gn < N) vb = B[(long)gn * K + k0 + c];
            Bs[c][r] = vb;
        }
        __syncthreads();
        #pragma unroll
        for (int kk = 0; kk < 16; kk++) {
            float4 a4 = *(const float4*)&As[kk][ty * 4];
            float4 b4 = *(const float4*)&Bs[kk][tx * 4];
            float a[4] = {a4.x, a4.y, a4.z, a4.w};
            float b[4] = {b4.x, b4.y, b4.z, b4.w};
            #pragma unroll
            for (int i = 0; i < 4; i++)
                #pragma unroll
                for (int j = 0; j < 4; j++) acc[i][j] += a[i] * b[j];
        }
        __syncthreads();
    }
    #pragma unroll
    for (int i = 0; i < 4; i++) {
        int gm = m0 + ty * 4 + i; if (gm >= M) continue;
        #pragma unroll
        for (int j = 0; j < 4; j++) {
            int gn = n0 + tx * 4 + j; if (gn >= N) continue;
            float v = acc[i][j] + (bias ? bias[gn] : 0.f);
            if (ACT == 1) v = sigmoidf_(v);
            if (ACT == 2) { v = fmaxf(v, 0.f); v = v * v; }
            C[(long)gm * N + gn] = v;
        }
    }
}

// C = A @ B (B row-major K x N). Batched. No bias/act.
__global__ __launch_bounds__(256) void gemm_nn_f32(
    const float* __restrict__ A, const float* __restrict__ B,
    float* __restrict__ C, int M, int N, int K, long sA, long sB, long sC)
{
    A += blockIdx.z * sA; B += blockIdx.z * sB; C += blockIdx.z * sC;
    __shared__ float As[16][68];
    __shared__ float Bs[16][68];
    const int m0 = blockIdx.y * 64, n0 = blockIdx.x * 64;
    const int tid = threadIdx.x;
    const int tx = tid & 15, ty = tid >> 4;
    float acc[4][4] = {};
    for (int k0 = 0; k0 < K; k0 += 16) {
        #pragma unroll
        for (int i = 0; i < 4; i++) {
            int idx = tid + i * 256;
            int r = idx >> 4, c = idx & 15;
            int gm = m0 + r;
            As[c][r] = (gm < M) ? A[(long)gm * K + k0 + c] : 0.f;
            int kk2 = idx >> 6, n = idx & 63;
            int gn = n0 + n;
            Bs[kk2][n] = (gn < N) ? B[(long)(k0 + kk2) * N + gn] : 0.f;
        }
        __syncthreads();
        #pragma unroll
        for (int kk = 0; kk < 16; kk++) {
            float4 a4 = *(const float4*)&As[kk][ty * 4];
            float4 b4 = *(const float4*)&Bs[kk][tx * 4];
            float a[4] = {a4.x, a4.y, a4.z, a4.w};
            float b[4] = {b4.x, b4.y, b4.z, b4.w};
            #pragma unroll
            for (int i = 0; i < 4; i++)
                #pragma unroll
                for (int j = 0; j < 4; j++) acc[i][j] += a[i] * b[j];
        }
        __syncthreads();
    }
    #pragma unroll
    for (int i = 0; i < 4; i++) {
        int gm = m0 + ty * 4 + i; if (gm >= M) continue;
        #pragma unroll
        for (int j = 0; j < 4; j++) {
            int gn = n0 + tx * 4 + j; if (gn >= N) continue;
            C[(long)gm * N + gn] = acc[i][j];
        }
    }
}

// ---------------------------------------------------------------------------
// GRU scan v2: barrier-free dataflow. 128 blocks x 64 threads (1 wave each).
// Wave w owns j in [6w, 6w+6): 18 rows of W_hh held fp32 in VGPRs.
// h for step t lives in hseq[t][1536] (fp32); unwritten entries are
// 0xFFFFFFFF (NaN sentinel, memset before launch). Lanes poll exactly the
// 24 dwords they consume — no flags, no fences, no barriers, no LDS.
// Owner lanes keep their h element fp32 in-register across steps, so the
// recurrence itself is exact; hseq is only the broadcast medium.
// ---------------------------------------------------------------------------
#define GRU_SENT 0xFFFFFFFFu
__global__ __launch_bounds__(64, 1) void gru_scan2_k(
    const float* __restrict__ xi, const float* __restrict__ Whh,
    const float* __restrict__ bhh, float* __restrict__ states,
    float* __restrict__ hseq)
{
    const int w = blockIdx.x;        // 0..127
    const int lane = threadIdx.x;    // 0..63
    const int jb = w * 6;

    // --- weights into VGPRs: wreg[g][jo][c] = Whh[g*768 + jb+jo][lane*12 + c]
    float wreg[3][6][12];
    #pragma unroll
    for (int g = 0; g < 3; g++)
        #pragma unroll
        for (int jo = 0; jo < 6; jo++) {
            const float* wp = Whh + (long)(g * Hn + jb + jo) * Hn + lane * 12;
            #pragma unroll
            for (int c = 0; c < 12; c += 4) {
                float4 v = *(const float4*)(wp + c);
                wreg[g][jo][c + 0] = v.x; wreg[g][jo][c + 1] = v.y;
                wreg[g][jo][c + 2] = v.z; wreg[g][jo][c + 3] = v.w;
            }
        }

    const bool own = (lane < 12);
    const int jo_own = lane >> 1, b_own = lane & 1;
    const int j_own = jb + jo_own;
    float bh0 = 0.f, bh1 = 0.f, bh2 = 0.f;
    if (own) { bh0 = bhh[j_own]; bh1 = bhh[Hn + j_own]; bh2 = bhh[2 * Hn + j_own]; }
    float hreg = 0.f;   // owner's exact fp32 h

    const uint* __restrict__ hsq = (const uint*)hseq;
    uint* __restrict__ hsqw = (uint*)hseq;

    for (int t = 0; t < Tn; t++) {
        // xi prefetch (independent of h availability)
        float xg0 = 0.f, xg1 = 0.f, xg2 = 0.f;
        if (own) {
            const float* xp = xi + ((long)b_own * Tn + t) * H3 + j_own;
            xg0 = xp[0]; xg1 = xp[Hn]; xg2 = xp[2 * Hn];
        }

        // poll this lane's 24 h dwords for step t
        const uint* hp = hsq + (long)t * 2 * Hn + lane * 12;
        uint hu[24];
        bool ready;
        do {
            #pragma unroll
            for (int b = 0; b < 2; b++)
                #pragma unroll
                for (int c = 0; c < 12; c++)
                    hu[b * 12 + c] = __hip_atomic_load(hp + b * Hn + c,
                                                      __ATOMIC_RELAXED, __HIP_MEMORY_SCOPE_AGENT);
            ready = true;
            #pragma unroll
            for (int i = 0; i < 24; i++) ready = ready && (hu[i] != GRU_SENT);
        } while (!ready);
        float hv[2][12];
        #pragma unroll
        for (int b = 0; b < 2; b++)
            #pragma unroll
            for (int c = 0; c < 12; c++) hv[b][c] = __uint_as_float(hu[b * 12 + c]);

        // dot products: 18 rows x 2 batches
        float acc[3][6][2];
        #pragma unroll
        for (int g = 0; g < 3; g++)
            #pragma unroll
            for (int jo = 0; jo < 6; jo++) {
                float s0 = 0.f, s1 = 0.f;
                #pragma unroll
                for (int c = 0; c < 12; c++) {
                    s0 += wreg[g][jo][c] * hv[0][c];
                    s1 += wreg[g][jo][c] * hv[1][c];
                }
                acc[g][jo][0] = s0; acc[g][jo][1] = s1;
            }

        // batch-folded butterfly: after level-1, lane parity selects batch
        float red[3][6];
        #pragma unroll
        for (int g = 0; g < 3; g++)
            #pragma unroll
            for (int jo = 0; jo < 6; jo++) {
                float keep = (lane & 1) ? acc[g][jo][1] : acc[g][jo][0];
                float send = (lane & 1) ? acc[g][jo][0] : acc[g][jo][1];
                red[g][jo] = keep + __shfl_xor(send, 1, 64);
            }
        #pragma unroll
        for (int m = 2; m < 64; m <<= 1)
            #pragma unroll
            for (int g = 0; g < 3; g++)
                #pragma unroll
                for (int jo = 0; jo < 6; jo++)
                    red[g][jo] += __shfl_xor(red[g][jo], m, 64);

        if (own) {
            float hr = 0.f, hz = 0.f, hn = 0.f;
            #pragma unroll
            for (int jo = 0; jo < 6; jo++)
                if (jo_own == jo) { hr = red[0][jo]; hz = red[1][jo]; hn = red[2][jo]; }
            hr += bh0; hz += bh1; hn += bh2;
            float rr = sigmoidf_(xg0 + hr);
            float zz = sigmoidf_(xg1 + hz);
            float nn = tanhf(xg2 + rr * hn);
            float hnew = (1.f - zz) * nn + zz * hreg;
            hreg = hnew;
            __hip_atomic_store(hsqw + (long)(t + 1) * 2 * Hn + b_own * Hn + j_own,
                               __float_as_uint(hnew),
                               __ATOMIC_RELAXED, __HIP_MEMORY_SCOPE_AGENT);
            states[((long)b_own * Tn + t) * Hn + j_own] = hnew;
        }
    }
}

// ---------------------------------------------------------------------------
// Attention softmax (strictly causal, in-place over scores buffer).
// ---------------------------------------------------------------------------
__global__ __launch_bounds__(256) void attn_softmax_k(float* __restrict__ attn)
{
    const int t = blockIdx.x, b = blockIdx.y;
    float* row = attn + ((long)b * Tn + t) * Tn;
    const int tid = threadIdx.x;
    __shared__ float red[256];
    const float scale = 0.0625f;  // 1/sqrt(256)
    float mx = -3.4e38f;
    for (int s = tid; s < t; s += 256) mx = fmaxf(mx, row[s] * scale);
    red[tid] = mx; __syncthreads();
    for (int st = 128; st > 0; st >>= 1) { if (tid < st) red[tid] = fmaxf(red[tid], red[tid + st]); __syncthreads(); }
    mx = red[0]; __syncthreads();
    float sum = 0.f;
    for (int s = tid; s < t; s += 256) { float e = __expf(row[s] * scale - mx); row[s] = e; sum += e; }
    red[tid] = sum; __syncthreads();
    for (int st = 128; st > 0; st >>= 1) { if (tid < st) red[tid] += red[tid + st]; __syncthreads(); }
    sum = red[0];
    float inv = 1.f / fmaxf(sum, 1e-6f);
    for (int s = tid; s < t; s += 256) row[s] *= inv;
    for (int s = t + tid; s < Tn; s += 256) row[s] = 0.f;
}

// top-2 of 16 router logits + 2-way softmax (tie -> lowest index, matches top_k)
__global__ void route_topk_k(const float* __restrict__ rl, float* __restrict__ rw, int* __restrict__ ridx)
{
    int n = blockIdx.x * blockDim.x + threadIdx.x;
    if (n >= NTOK) return;
    const float* r = rl + (long)n * Gn;
    float v1 = -3.4e38f; int i1 = 0;
    #pragma unroll
    for (int g = 0; g < Gn; g++) { float v = r[g]; if (v > v1) { v1 = v; i1 = g; } }
    float v2 = -3.4e38f; int i2 = 0;
    #pragma unroll
    for (int g = 0; g < Gn; g++) { if (g == i1) continue; float v = r[g]; if (v > v2) { v2 = v; i2 = g; } }
    float e2 = __expf(v2 - v1);
    float s = 1.f + e2;
    rw[n * 2] = 1.f / s; rw[n * 2 + 1] = e2 / s;
    ridx[n * 2] = i1; ridx[n * 2 + 1] = i2;
}

// routed basis: out[n][r] += w_g * (inp[n,:] @ cw[g,:,r] + cb[g,r]) for g in top2(n)
// grid: (G, NTOK/256). Accumulate via atomicAdd (out pre-zeroed).
__global__ __launch_bounds__(256) void routed_basis_k(
    const float* __restrict__ inp, const float* __restrict__ cw, const float* __restrict__ cb,
    const float* __restrict__ rw, const int* __restrict__ ridx,
    float* __restrict__ out, int D)
{
    const int g = blockIdx.x;
    const int t0 = blockIdx.y * 256;
    __shared__ float srow[Hn];
    __shared__ float part[4][64];
    const int r = threadIdx.x & 63, dq = threadIdx.x >> 6;
    const float* cwg = cw + (long)g * D * Rn;
    const int dlen = D >> 2;
    for (int ti = 0; ti < 256; ti++) {
        const int n = t0 + ti;
        float wt = 0.f;
        if (ridx[n * 2] == g) wt = rw[n * 2];
        else if (ridx[n * 2 + 1] == g) wt = rw[n * 2 + 1];
        if (wt == 0.f) continue;            // block-uniform
        __syncthreads();
        for (int d = threadIdx.x; d < D; d += 256) srow[d] = inp[(long)n * D + d];
        __syncthreads();
        float p = 0.f;
        const int dbeg = dq * dlen;
        for (int d = dbeg; d < dbeg + dlen; d++) p += srow[d] * cwg[(long)d * Rn + r];
        part[dq][r] = p;
        __syncthreads();
        if (dq == 0) {
            float sv = part[0][r] + part[1][r] + part[2][r] + part[3][r] + cb[g * Rn + r];
            atomicAdd(&out[(long)n * Rn + r], wt * sv);
        }
    }
}

__global__ void comb_k(const float* __restrict__ bb, const float* __restrict__ mb,
                       const float* __restrict__ bg, const float* __restrict__ bs_ptr,
                       float* __restrict__ comb)
{
    int i = blockIdx.x * 256 + threadIdx.x;
    if (i < NTOK * Rn) comb[i] = bb[i] + bs_ptr[0] * (bg[i] * mb[i]);
}

__global__ void ftotal_k(const float* __restrict__ bf, const float* __restrict__ dl,
                         unsigned short* __restrict__ outb)
{
    int i = blockIdx.x * 256 + threadIdx.x;
    if (i < NTOK * En) outb[i] = f2bf(bf[i] + dl[i]);
}

__global__ void embconv_k(const float* __restrict__ emb, unsigned short* __restrict__ outb)
{
    long i = (long)(blockIdx.x * 256 + threadIdx.x) * 4;
    const long nTot = (long)Vn * En;
    for (; i < nTot; i += (long)gridDim.x * 256 * 4) {
        float4 v = *(const float4*)(emb + i);
        ushort4 u;
        u.x = f2bf(v.x); u.y = f2bf(v.y); u.z = f2bf(v.z); u.w = f2bf(v.w);
        *(ushort4*)(outb + i) = u;
    }
}

// ---------------------------------------------------------------------------
// Logits GEMM: C(2048,32000) = A(2048,512)bf16 @ B(32000,512)bf16^T + bias.
// m97-style: 128x128 tile, BK=32, 4 waves (2x2), 16x16x32 bf16 MFMA,
// global_load_lds width-16 staging.
// ---------------------------------------------------------------------------
typedef const __attribute__((address_space(1))) void* as1cv_t;
typedef __attribute__((address_space(3))) void* as3v_t;
__device__ __forceinline__ void gload_lds16(const void* g, void* l) {
    __builtin_amdgcn_global_load_lds((as1cv_t)g, (as3v_t)l, 16, 0, 0);
}

__global__ __launch_bounds__(256) void logits_mfma_k(
    const unsigned short* __restrict__ Abf, const unsigned short* __restrict__ Bbf,
    const float* __restrict__ bias, float* __restrict__ C)
{
    __shared__ __align__(16) unsigned short As[128 * 32];
    __shared__ __align__(16) unsigned short Bs[128 * 32];
    const int n0 = blockIdx.x * 128;
    const int m0 = blockIdx.y * 128;
    const int tid = threadIdx.x;
    const int lane = tid & 63, wv = tid >> 6;
    const int wr = wv >> 1, wc = wv & 1;
    f32x4 zero4 = {0.f, 0.f, 0.f, 0.f};
    f32x4 acc[4][4];
    #pragma unroll
    for (int i = 0; i < 4; i++)
        #pragma unroll
        for (int j = 0; j < 4; j++) acc[i][j] = zero4;

    const int lrow = lane & 15, lko = (lane >> 4) * 8;

    for (int k0 = 0; k0 < En; k0 += 32) {
        __syncthreads();
        #pragma unroll
        for (int i = 0; i < 2; i++) {
            int base = i * 4096 + wv * 1024;     // wave-uniform LDS byte offset
            int p = base + lane * 16;            // this lane's element position
            int row = p >> 6, cb = p & 63;       // 64 B per tile row (32 bf16)
            gload_lds16((const char*)Abf + ((long)(m0 + row) * En + k0) * 2 + cb, (char*)As + base);
            gload_lds16((const char*)Bbf + ((long)(n0 + row) * En + k0) * 2 + cb, (char*)Bs + base);
        }
        __syncthreads();
        short8 af[4], bfr[4];
        #pragma unroll
        for (int m = 0; m < 4; m++)
            af[m] = *(const short8*)((const char*)As + (wr * 64 + m * 16 + lrow) * 64 + lko * 2);
        #pragma unroll
        for (int n = 0; n < 4; n++)
            bfr[n] = *(const short8*)((const char*)Bs + (wc * 64 + n * 16 + lrow) * 64 + lko * 2);
        #pragma unroll
        for (int m = 0; m < 4; m++)
            #pragma unroll
            for (int n = 0; n < 4; n++)
                acc[m][n] = __builtin_amdgcn_mfma_f32_16x16x32_bf16(af[m], bfr[n], acc[m][n], 0, 0, 0);
    }
    const int orow = (lane >> 4) * 4, ocol = lane & 15;
    #pragma unroll
    for (int m = 0; m < 4; m++) {
        #pragma unroll
        for (int n = 0; n < 4; n++) {
            int col = n0 + wc * 64 + n * 16 + ocol;
            float bv = bias[col];
            int rbase = m0 + wr * 64 + m * 16 + orow;
            #pragma unroll
            for (int r2 = 0; r2 < 4; r2++)
                C[(long)(rbase + r2) * Vn + col] = acc[m][n][r2] + bv;
        }
    }
}

// copy mechanism: logits[b,t, ids[b,s]] += attn[b,t,s] * eg[b,t] * exact_scale
__global__ __launch_bounds__(256) void copy_scatter_k(
    float* __restrict__ logits, const float* __restrict__ attn,
    const float* __restrict__ eg, const int* __restrict__ ids,
    const float* __restrict__ esc)
{
    const int n = blockIdx.x;
    const int b = n >> 10, t = n & 1023;
    const float g = eg[n] * esc[0];
    const float* arow = attn + ((long)b * Tn + t) * Tn;
    float* lrow = logits + (long)n * Vn;
    const int* idrow = ids + b * Tn;
    for (int s = threadIdx.x; s < t; s += 256) {
        float a = arow[s];
        atomicAdd(lrow + idrow[s], a * g);
    }
}

// ---------------------------------------------------------------------------
extern "C" void kernel_launch(void* const* d_in, const int* in_sizes, int n_in,
                              void* d_out, int out_size, void* d_ws, size_t ws_size,
                              hipStream_t stream)
{
    const int*   ids      = (const int*)  d_in[0];
    const float* emb      = (const float*)d_in[1];
    const float* W_ih     = (const float*)d_in[2];
    const float* W_hh     = (const float*)d_in[3];
    const float* b_ih     = (const float*)d_in[4];
    const float* b_hh     = (const float*)d_in[5];
    const float* Wq       = (const float*)d_in[6];
    const float* bq       = (const float*)d_in[7];
    const float* Wk       = (const float*)d_in[8];
    const float* bk       = (const float*)d_in[9];
    const float* Wg       = (const float*)d_in[10];
    const float* bg       = (const float*)d_in[11];
    const float* Whf      = (const float*)d_in[12];
    const float* bhf      = (const float*)d_in[13];
    const float* Whp      = (const float*)d_in[14];
    const float* bhp      = (const float*)d_in[15];
    const float* Wr       = (const float*)d_in[16];
    const float* br       = (const float*)d_in[17];
    const float* base_cw  = (const float*)d_in[18];
    const float* base_cb  = (const float*)d_in[19];
    const float* mem_cw   = (const float*)d_in[20];
    const float* mem_cb   = (const float*)d_in[21];
    const float* Wbg      = (const float*)d_in[22];
    const float* bbg      = (const float*)d_in[23];
    const float* Wbu      = (const float*)d_in[24];
    const float* out_bias = (const float*)d_in[25];
    const float* esc      = (const float*)d_in[26];
    const float* bsc      = (const float*)d_in[27];
    float* logits = (float*)d_out;

    char* ws = (char*)d_ws;
    size_t off = 0;
    auto alloc = [&](size_t bytes) -> void* {
        void* p = ws + off; off = (off + bytes + 255) & ~(size_t)255; return p;
    };
    float* xi     = (float*)alloc((size_t)NTOK * H3 * 4);   // reused as 'head' after GRU
    float* head   = xi;                                     // 2048*2048 <= 2048*2304
    float* states = (float*)alloc((size_t)NTOK * Hn * 4);
    float* hseq   = (float*)alloc((size_t)(Tn + 1) * 2 * Hn * 4);  // sentinel dataflow buffer
    float* bfeat  = (float*)alloc((size_t)NTOK * En * 4);
    float* qb     = (float*)alloc((size_t)NTOK * Mn * 4);
    float* kb     = (float*)alloc((size_t)NTOK * Mn * 4);
    float* attn   = (float*)alloc((size_t)Bn * Tn * Tn * 4);
    float* mem    = (float*)alloc((size_t)NTOK * Hn * 4);
    float* rl     = (float*)alloc((size_t)NTOK * Gn * 4);
    float* rw     = (float*)alloc((size_t)NTOK * 2 * 4);
    int*   ridx   = (int*)  alloc((size_t)NTOK * 2 * 4);
    float* bgate  = (float*)alloc((size_t)NTOK * Rn * 4);
    float* egb    = (float*)alloc((size_t)NTOK * 4);
    float* bb     = (float*)alloc((size_t)NTOK * Rn * 4);   // 524288 B (256-mult, mb adjacent)
    float* mb     = (float*)alloc((size_t)NTOK * Rn * 4);
    float* comb   = (float*)alloc((size_t)NTOK * Rn * 4);
    float* delta  = (float*)alloc((size_t)NTOK * En * 4);
    unsigned short* fbf   = (unsigned short*)alloc((size_t)NTOK * En * 2);
    unsigned short* embbf = (unsigned short*)alloc((size_t)Vn * En * 2);
    (void)in_sizes; (void)n_in; (void)out_size; (void)ws_size;

    // hseq[0] = h0 = 0 ; hseq[1..1024] = sentinel NaN ; basis accumulators = 0
    hipMemsetAsync(hseq, 0, (size_t)2 * Hn * 4, stream);
    hipMemsetAsync(hseq + 2 * Hn, 0xFF, (size_t)Tn * 2 * Hn * 4, stream);
    hipMemsetAsync(bb, 0, (size_t)NTOK * Rn * 4 * 2, stream);

    // emb -> bf16 (for tied-embedding MFMA GEMM)
    embconv_k<<<2048, 256, 0, stream>>>(emb, embbf);
    // xi = emb[ids] @ W_ih^T + b_ih   (gathered A)
    gemm_nt_f32<0><<<dim3(H3 / 64, NTOK / 64, 1), 256, 0, stream>>>(
        emb, W_ih, xi, b_ih, NTOK, H3, En, 0, 0, 0, ids);
    // GRU scan (barrier-free sentinel dataflow)
    gru_scan2_k<<<128, 64, 0, stream>>>(xi, W_hh, b_hh, states, hseq);
    // head = relu(states @ Whf^T + bhf)^2   (overwrites xi buffer)
    gemm_nt_f32<2><<<dim3(2048 / 64, NTOK / 64), 256, 0, stream>>>(
        states, Whf, head, bhf, NTOK, 4 * En, Hn, 0, 0, 0, nullptr);
    // base_feat = head @ Whp^T + bhp
    gemm_nt_f32<0><<<dim3(En / 64, NTOK / 64), 256, 0, stream>>>(
        head, Whp, bfeat, bhp, NTOK, En, 4 * En, 0, 0, 0, nullptr);
    // router
    gemm_nt_f32<0><<<dim3(1, NTOK / 64), 256, 0, stream>>>(
        states, Wr, rl, br, NTOK, Gn, Hn, 0, 0, 0, nullptr);
    route_topk_k<<<NTOK / 256, 256, 0, stream>>>(rl, rw, ridx);
    // q, k
    gemm_nt_f32<0><<<dim3(Mn / 64, NTOK / 64), 256, 0, stream>>>(
        states, Wq, qb, bq, NTOK, Mn, Hn, 0, 0, 0, nullptr);
    gemm_nt_f32<0><<<dim3(Mn / 64, NTOK / 64), 256, 0, stream>>>(
        states, Wk, kb, bk, NTOK, Mn, Hn, 0, 0, 0, nullptr);
    // scores (scale folded into softmax), then causal softmax in-place
    gemm_nt_f32<0><<<dim3(Tn / 64, Tn / 64, Bn), 256, 0, stream>>>(
        qb, kb, attn, nullptr, Tn, Tn, Mn, (long)Tn * Mn, (long)Tn * Mn, (long)Tn * Tn, nullptr);
    attn_softmax_k<<<dim3(Tn, Bn), 256, 0, stream>>>(attn);
    // mem_states = attn @ states
    gemm_nn_f32<<<dim3(Hn / 64, Tn / 64, Bn), 256, 0, stream>>>(
        attn, states, mem, Tn, Hn, Tn, (long)Tn * Tn, (long)Tn * Hn, (long)Tn * Hn);
    // gates
    gemm_nt_f32<1><<<dim3(1, NTOK / 64), 256, 0, stream>>>(
        states, Wbg, bgate, bbg, NTOK, Rn, Hn, 0, 0, 0, nullptr);
    gemm_nt_f32<1><<<dim3(1, NTOK / 64), 256, 0, stream>>>(
        states, Wg, egb, bg, NTOK, 1, Hn, 0, 0, 0, nullptr);
    // routed bases (top-2 sparse)
    routed_basis_k<<<dim3(Gn, NTOK / 256), 256, 0, stream>>>(bfeat, base_cw, base_cb, rw, ridx, bb, En);
    routed_basis_k<<<dim3(Gn, NTOK / 256), 256, 0, stream>>>(mem, mem_cw, mem_cb, rw, ridx, mb, Hn);
    // delta = (bb + bs*bgate*mb) @ Wbu^T ; f_total = bf16(base_feat + delta)
    comb_k<<<(NTOK * Rn + 255) / 256, 256, 0, stream>>>(bb, mb, bgate, bsc, comb);
    gemm_nt_f32<0><<<dim3(En / 64, NTOK / 64), 256, 0, stream>>>(
        comb, Wbu, delta, nullptr, NTOK, En, Rn, 0, 0, 0, nullptr);
    ftotal_k<<<(NTOK * En + 255) / 256, 256, 0, stream>>>(bfeat, delta, fbf);
    // logits = f_total @ emb^T + out_bias  (both emb matmuls folded into one)
    logits_mfma_k<<<dim3(Vn / 128, NTOK / 128), 256, 0, stream>>>(fbf, embbf, out_bias, logits);
    // copy mechanism scatter
    copy_scatter_k<<<NTOK, 256, 0, stream>>>(logits, attn, egb, ids, esc);
}